// Round 1
// baseline (122.184 us; speedup 1.0000x reference)
//
#include <hip/hip_runtime.h>

// Problem constants
constexpr int N = 8192;
constexpr int C = 2048;
constexpr int SEG = N / 4;                 // 2048 rows per segment
constexpr int ND = N + 4;                  // 8196
constexpr int ADJ_CHUNKS = ND / 4;         // 2049 float4 per adj row
constexpr size_t XNEW_ELEMS = (size_t)ND * C;  // 16785408

// ---------------------------------------------------------------------------
// Zero the centers region of x_new (used as the atomic numerator accumulator)
// and the 4 per-segment weight sums in ws. Must run every call (no re-poison).
__global__ __launch_bounds__(256) void k_zero(float* __restrict__ xnew,
                                              float* __restrict__ wseg) {
    int idx = blockIdx.x * 256 + threadIdx.x;
    if (idx < 4 * C) xnew[(size_t)N * C + idx] = 0.0f;
    if (idx < 4) wseg[idx] = 0.0f;
}

// ---------------------------------------------------------------------------
// One pass over x: per-row attention score, copy row into x_new head,
// accumulate w_row * x_row into the centers numerator (in d_out) + W_i (ws).
// Block = 256 threads = 4 waves; each wave owns 4 consecutive rows.
// Lane l owns columns 4*(l + 64q)+{0..3}, q = 0..7  (all 2048 cols per wave).
__global__ __launch_bounds__(256) void k_att(const float* __restrict__ x,
                                             const float* __restrict__ attw,
                                             const float* __restrict__ attb,
                                             float* __restrict__ xnew,
                                             float* __restrict__ wseg) {
    __shared__ float lnum[4][C];           // 32 KiB: per-wave partial numerators

    const int tid  = threadIdx.x;
    const int wave = tid >> 6;
    const int lane = tid & 63;
    const int row0 = blockIdx.x * 16;      // 16 rows per block (512 blocks)
    const int seg  = row0 >> 11;           // 2048 rows per segment
    const float bias = attb[0];

    // att_w fragment for this lane's 32 columns
    float4 wv[8];
#pragma unroll
    for (int q = 0; q < 8; ++q)
        wv[q] = reinterpret_cast<const float4*>(attw)[lane + 64 * q];

    float acc[32];
#pragma unroll
    for (int k = 0; k < 32; ++k) acc[k] = 0.0f;
    float wacc = 0.0f;

    for (int r = 0; r < 4; ++r) {
        const int row = row0 + wave * 4 + r;
        const float4* xrow = reinterpret_cast<const float4*>(x + (size_t)row * C);
        float4* orow = reinterpret_cast<float4*>(xnew + (size_t)row * C);

        float4 xv[8];
        float dot = 0.0f;
#pragma unroll
        for (int q = 0; q < 8; ++q) {
            xv[q] = xrow[lane + 64 * q];
            dot += xv[q].x * wv[q].x + xv[q].y * wv[q].y +
                   xv[q].z * wv[q].z + xv[q].w * wv[q].w;
        }
        // full 64-lane butterfly reduce -> every lane holds the row dot
#pragma unroll
        for (int off = 32; off > 0; off >>= 1) dot += __shfl_xor(dot, off, 64);
        const float wrow = dot + bias;
        wacc += wrow;
#pragma unroll
        for (int q = 0; q < 8; ++q) {
            acc[4 * q + 0] += wrow * xv[q].x;
            acc[4 * q + 1] += wrow * xv[q].y;
            acc[4 * q + 2] += wrow * xv[q].z;
            acc[4 * q + 3] += wrow * xv[q].w;
            orow[lane + 64 * q] = xv[q];   // x_new head copy
        }
    }

    // Each wave writes its full 2048-entry partial (assignment, fully covered).
#pragma unroll
    for (int q = 0; q < 8; ++q) {
        reinterpret_cast<float4*>(&lnum[wave][0])[lane + 64 * q] =
            make_float4(acc[4 * q + 0], acc[4 * q + 1], acc[4 * q + 2], acc[4 * q + 3]);
    }
    __syncthreads();

    // Combine 4 wave partials, one global atomic per column per block.
    for (int c = tid; c < C; c += 256) {
        float s = lnum[0][c] + lnum[1][c] + lnum[2][c] + lnum[3][c];
        atomicAdd(&xnew[(size_t)(N + seg) * C + c], s);
    }
    if (tid == (wave << 6)) {              // lane 0 of each wave; wacc is wave-uniform
        if (wave == 0) atomicAdd(&wseg[seg], wacc * 1.0f);
        else           atomicAdd(&wseg[seg], wacc);
    }
}

// ---------------------------------------------------------------------------
// centers /= W_i  (in place in d_out)
__global__ __launch_bounds__(256) void k_div(float* __restrict__ xnew,
                                             const float* __restrict__ wseg) {
    int idx = blockIdx.x * 256 + threadIdx.x;
    if (idx < 4 * C) {
        int i = idx >> 11;
        xnew[(size_t)N * C + idx] /= wseg[i];
    }
}

// ---------------------------------------------------------------------------
// adj: single streaming float4 store per 16B; value from (row, chunk) pattern.
__global__ __launch_bounds__(256) void k_adj(float* __restrict__ adj) {
    const unsigned TOTAL4 = (unsigned)ND * ADJ_CHUNKS;   // 16,793,604
    const unsigned i4 = blockIdx.x * 256u + threadIdx.x;
    if (i4 >= TOTAL4) return;
    const unsigned row   = i4 / ADJ_CHUNKS;              // const-div -> mul_hi
    const unsigned chunk = i4 - row * ADJ_CHUNKS;

    const float c_diag = 0.5f;                 // d_j^2, d_j = 2^-1/2
    const float c_link = 0.015609763f;         // 1/sqrt(2*2052)
    const float c_blk  = 1.0f / 2052.0f;       // d_c^2

    float4 v = make_float4(0.f, 0.f, 0.f, 0.f);
    if (row < (unsigned)N) {
        if (chunk == (row >> 2)) (&v.x)[row & 3] = c_diag;          // diagonal
        if (chunk == 2048u)      (&v.x)[row >> 11] = c_link;        // row -> its center
    } else {
        const unsigned a = row - N;
        if (chunk == 2048u)            v = make_float4(c_blk, c_blk, c_blk, c_blk);
        else if ((chunk >> 9) == a)    v = make_float4(c_link, c_link, c_link, c_link);
    }
    reinterpret_cast<float4*>(adj)[i4] = v;
}

// ---------------------------------------------------------------------------
extern "C" void kernel_launch(void* const* d_in, const int* in_sizes, int n_in,
                              void* d_out, int out_size, void* d_ws, size_t ws_size,
                              hipStream_t stream) {
    const float* x    = (const float*)d_in[0];
    const float* attw = (const float*)d_in[1];
    const float* attb = (const float*)d_in[2];
    float* xnew = (float*)d_out;                   // [8196, 2048]
    float* adj  = (float*)d_out + XNEW_ELEMS;      // [8196, 8196]
    float* wseg = (float*)d_ws;                    // 4 floats

    // adj is independent of everything else; launch its big write first so it
    // overlaps nothing but keeps the memory system busy end-to-end.
    {
        const unsigned TOTAL4 = (unsigned)ND * ADJ_CHUNKS;
        const unsigned blocks = (TOTAL4 + 255u) / 256u;  // 65601
        k_adj<<<blocks, 256, 0, stream>>>(adj);
    }
    k_zero<<<32, 256, 0, stream>>>(xnew, wseg);
    k_att<<<N / 16, 256, 0, stream>>>(x, attw, attb, xnew, wseg);
    k_div<<<32, 256, 0, stream>>>(xnew, wseg);
}

// Round 2
// 91.868 us; speedup vs baseline: 1.3300x; 1.3300x over previous
//
#include <hip/hip_runtime.h>

// Problem constants
constexpr int N = 8192;
constexpr int C = 2048;
constexpr int ND = N + 4;                       // 8196
constexpr size_t XNEW_ELEMS = (size_t)ND * C;   // 16785408
constexpr size_t ADJ_ELEMS  = (size_t)ND * ND;  // 67174416

#define C_DIAG 0.5f
#define C_LINK 0.015609764f                     /* 1/sqrt(2*2052) */
#define C_BLK  (1.0f / 2052.0f)

// ---------------------------------------------------------------------------
// Scatter adj nonzeros (after the bulk memset-to-zero).
//   t in [0,N):           diagonal 0.5 and row->center link
//   t in [N, N+4*2052):   the 4 center rows (2048 links + 4 center-block each)
__global__ __launch_bounds__(256) void k_adj_nz(float* __restrict__ adj) {
    const int t = blockIdx.x * 256 + threadIdx.x;
    if (t < N) {
        adj[(size_t)t * ND + t] = C_DIAG;                 // diagonal
        adj[(size_t)t * ND + N + (t >> 11)] = C_LINK;     // row -> its center
    } else if (t < N + 4 * 2052) {
        const int u = t - N;
        const int i = u / 2052;                           // center index 0..3
        const int j = u - i * 2052;
        const size_t rowb = (size_t)(N + i) * ND;
        if (j < 2048) adj[rowb + i * 2048 + j] = C_LINK;  // center -> segment
        else          adj[rowb + N + (j - 2048)] = C_BLK; // 4x4 center block
    }
}

// ---------------------------------------------------------------------------
// One pass over x: per-row attention score, copy row into x_new head,
// accumulate w_row * x_row into a per-block partial. Block = 256 thr = 4
// waves; each wave owns 4 consecutive rows; block covers 16 rows.
// USE_WS: write per-block partials to ws (no atomics). else: atomic fallback.
template <bool USE_WS>
__global__ __launch_bounds__(256) void k_att(const float* __restrict__ x,
                                             const float* __restrict__ attw,
                                             const float* __restrict__ attb,
                                             float* __restrict__ xnew,
                                             float* __restrict__ part,
                                             float* __restrict__ wpart) {
    __shared__ float lnum[4][C];               // 32 KiB per-wave partials
    __shared__ float lw[4];

    const int tid  = threadIdx.x;
    const int wave = tid >> 6;
    const int lane = tid & 63;
    const int row0 = blockIdx.x * 16;
    const int seg  = blockIdx.x >> 7;          // 128 blocks per segment
    const float bias = attb[0];

    float4 wv[8];
#pragma unroll
    for (int q = 0; q < 8; ++q)
        wv[q] = reinterpret_cast<const float4*>(attw)[lane + 64 * q];

    float acc[32];
#pragma unroll
    for (int k = 0; k < 32; ++k) acc[k] = 0.0f;
    float wacc = 0.0f;

    for (int r = 0; r < 4; ++r) {
        const int row = row0 + wave * 4 + r;
        const float4* xrow = reinterpret_cast<const float4*>(x + (size_t)row * C);
        float4* orow = reinterpret_cast<float4*>(xnew + (size_t)row * C);

        float4 xv[8];
        float dot = 0.0f;
#pragma unroll
        for (int q = 0; q < 8; ++q) {
            xv[q] = xrow[lane + 64 * q];
            dot += xv[q].x * wv[q].x + xv[q].y * wv[q].y +
                   xv[q].z * wv[q].z + xv[q].w * wv[q].w;
        }
#pragma unroll
        for (int off = 32; off > 0; off >>= 1) dot += __shfl_xor(dot, off, 64);
        const float wrow = dot + bias;
        wacc += wrow;
#pragma unroll
        for (int q = 0; q < 8; ++q) {
            acc[4 * q + 0] += wrow * xv[q].x;
            acc[4 * q + 1] += wrow * xv[q].y;
            acc[4 * q + 2] += wrow * xv[q].z;
            acc[4 * q + 3] += wrow * xv[q].w;
            orow[lane + 64 * q] = xv[q];       // x_new head copy
        }
    }

#pragma unroll
    for (int q = 0; q < 8; ++q)
        reinterpret_cast<float4*>(&lnum[wave][0])[lane + 64 * q] =
            make_float4(acc[4 * q], acc[4 * q + 1], acc[4 * q + 2], acc[4 * q + 3]);
    if (lane == 0) lw[wave] = wacc;            // wacc is wave-uniform
    __syncthreads();

    const float4* l0 = reinterpret_cast<const float4*>(&lnum[0][0]);
    const float4* l1 = reinterpret_cast<const float4*>(&lnum[1][0]);
    const float4* l2 = reinterpret_cast<const float4*>(&lnum[2][0]);
    const float4* l3 = reinterpret_cast<const float4*>(&lnum[3][0]);
#pragma unroll
    for (int c4 = tid; c4 < C / 4; c4 += 256) {
        float4 a = l0[c4], b = l1[c4], cc = l2[c4], d = l3[c4];
        float4 s = make_float4(a.x + b.x + cc.x + d.x, a.y + b.y + cc.y + d.y,
                               a.z + b.z + cc.z + d.z, a.w + b.w + cc.w + d.w);
        if constexpr (USE_WS) {
            reinterpret_cast<float4*>(part + (size_t)blockIdx.x * C)[c4] = s;
        } else {
            float* dst = &xnew[(size_t)(N + seg) * C + 4 * c4];
            atomicAdd(dst + 0, s.x); atomicAdd(dst + 1, s.y);
            atomicAdd(dst + 2, s.z); atomicAdd(dst + 3, s.w);
        }
    }
    if (tid == 0) {
        const float wb = lw[0] + lw[1] + lw[2] + lw[3];
        if constexpr (USE_WS) wpart[blockIdx.x] = wb;
        else                  atomicAdd(&wpart[seg], wb);
    }
}

// ---------------------------------------------------------------------------
// centers[seg][c] = sum_k part[seg*128+k][c] / sum_k wpart[seg*128+k]
__global__ __launch_bounds__(256) void k_centers(const float* __restrict__ part,
                                                 const float* __restrict__ wpart,
                                                 float* __restrict__ xnew) {
    const int idx = blockIdx.x * 256 + threadIdx.x;   // 0..8191
    const int seg = idx >> 11;
    const int c   = idx & 2047;
    float wsum = 0.0f;
#pragma unroll 8
    for (int k = 0; k < 128; ++k) wsum += wpart[seg * 128 + k];
    float s = 0.0f;
#pragma unroll 8
    for (int k = 0; k < 128; ++k) s += part[(size_t)(seg * 128 + k) * C + c];
    xnew[(size_t)(N + seg) * C + c] = s / wsum;
}

// ---------------------------------------------------------------------------
// Fallback-path helpers (used only if ws is tiny): zero + divide.
__global__ __launch_bounds__(256) void k_zero(float* __restrict__ xnew,
                                              float* __restrict__ wseg) {
    int idx = blockIdx.x * 256 + threadIdx.x;
    if (idx < 4 * C) xnew[(size_t)N * C + idx] = 0.0f;
    if (idx < 4) wseg[idx] = 0.0f;
}
__global__ __launch_bounds__(256) void k_div(float* __restrict__ xnew,
                                             const float* __restrict__ wseg) {
    int idx = blockIdx.x * 256 + threadIdx.x;
    if (idx < 4 * C) xnew[(size_t)N * C + idx] /= wseg[idx >> 11];
}

// ---------------------------------------------------------------------------
extern "C" void kernel_launch(void* const* d_in, const int* in_sizes, int n_in,
                              void* d_out, int out_size, void* d_ws, size_t ws_size,
                              hipStream_t stream) {
    const float* x    = (const float*)d_in[0];
    const float* attw = (const float*)d_in[1];
    const float* attb = (const float*)d_in[2];
    float* xnew = (float*)d_out;                   // [8196, 2048]
    float* adj  = (float*)d_out + XNEW_ELEMS;      // [8196, 8196]

    // adj: bulk zero via the fast fill path, then scatter ~66 KB of nonzeros.
    hipMemsetAsync(adj, 0, ADJ_ELEMS * sizeof(float), stream);
    {
        const int nz_threads = N + 4 * 2052;       // 16400
        k_adj_nz<<<(nz_threads + 255) / 256, 256, 0, stream>>>(adj);
    }

    const size_t ws_need = (1024 + (size_t)512 * C) * sizeof(float);  // ~4.2 MB
    if (ws_size >= ws_need) {
        float* wpart = (float*)d_ws;               // [512]
        float* part  = (float*)d_ws + 1024;        // [512][C]
        k_att<true><<<N / 16, 256, 0, stream>>>(x, attw, attb, xnew, part, wpart);
        k_centers<<<32, 256, 0, stream>>>(part, wpart, xnew);
    } else {                                        // atomic fallback
        float* wseg = (float*)d_ws;                // [4]
        k_zero<<<32, 256, 0, stream>>>(xnew, wseg);
        k_att<false><<<N / 16, 256, 0, stream>>>(x, attw, attb, xnew, nullptr, wseg);
        k_div<<<32, 256, 0, stream>>>(xnew, wseg);
    }
}